// Round 9
// baseline (256.607 us; speedup 1.0000x reference)
//
#include <hip/hip_runtime.h>
#include <stdint.h>

// Problem constants
#define BATCH 4
#define SEQ   2048
#define DIM_  1024
#define NHEAD 16
#define HDIM  64

// 0.125 (1/sqrt(64)) * log2(e): folded into Q so softmax is exp2(S) directly.
#define QSC 0.18033688011112042f

typedef __attribute__((ext_vector_type(8)))  short bf8;    // 8 bf16 raw bits
typedef __attribute__((ext_vector_type(4)))  float f4;
typedef __attribute__((ext_vector_type(16))) float f16v;
typedef __attribute__((ext_vector_type(2)))  unsigned int u2;
typedef __attribute__((ext_vector_type(4)))  unsigned int u4;

#define MFMA(a, b, c)   __builtin_amdgcn_mfma_f32_16x16x32_bf16(a, b, c, 0, 0, 0)
#define MFMA32(a, b, c) __builtin_amdgcn_mfma_f32_32x32x16_bf16(a, b, c, 0, 0, 0)

// lgkm-only workgroup barrier: global prefetch stream stays in flight.
#define BAR_LGKM() asm volatile("s_waitcnt lgkmcnt(0)\n\ts_barrier" ::: "memory")

static __device__ __forceinline__ short f2b(float f) {
    uint32_t u = __builtin_bit_cast(uint32_t, f);
    u = (u + 0x7FFFu + ((u >> 16) & 1u)) >> 16;   // RNE
    return (short)u;
}

// packed f32x2 -> bf16x2 in one VALU op (T12; RNE, same as f2b)
static __device__ __forceinline__ uint32_t cvtpk(float lo, float hi) {
    uint32_t r;
    asm("v_cvt_pk_bf16_f32 %0, %1, %2" : "=v"(r) : "v"(lo), "v"(hi));
    return r;
}

// --------------------------------------------------------- reg-staged GEMM core
// r9: cvt_all DELETED. Both GEMMs convert fp32 operands during staging
// (float4 load -> v_cvt_pk_bf16_f32 -> ds_write_b128), removing the 63 MB
// fp32 read + 31 MB bf16 write + re-read round-trip and one kernel launch.
// Tile 128x128, BK=32, 4 waves (2M x 2N), per-wave 64x64 (r8 geometry).
// DOUBLE-buffered 32 KB LDS, ONE BAR_LGKM per K-step (flash-proven pattern:
// lgkmcnt(0)+s_barrier makes all waves' ds_writes visible; vmcnt prefetch
// stream stays in flight across the barrier; compiler inserts counted vmcnt
// waits for the reg loads automatically). Per K-step: read frags(t) ->
// ds_write(t+1 from regs) -> issue loads(t+2) -> MFMA -> BAR_LGKM -> swap.
// WAR safe: oth's reads (step t-1) retired at that step's lgkmcnt(0).
// LDS layout + swizzle = r0/r8 proven: thread tid stages source chunk
// (tid&3)^((tid>>3)&3) of row tid>>2 at linear dest tid*8; readers address
// chunk quad^((l16>>1)&3) -> content = quad (0 bank conflicts, verified).
#define NT2  32      /* K tiles: 1024/32 */
#define BUF2 8192    /* shorts per buffer: A 4096 + B 4096 = 16 KB */

#define GEO_PROLOG()                                                          \
    __shared__ __align__(16) short lds[2 * BUF2];                             \
    const int tid  = threadIdx.x;                                             \
    const int lane = tid & 63;                                                \
    const int wave = tid >> 6;                                                \
    const int quad = lane >> 4, l16 = lane & 15;                              \
    const int wr = wave >> 1, wc = wave & 1;                                  \
    const int m0 = blockIdx.y * 128;                                          \
    const int n0 = blockIdx.x * 128;                                          \
    const int srow = tid >> 2;                                                \
    const int sx   = ((tid & 3) ^ ((tid >> 3) & 3)) * 8;  /* swizzled src */  \
    const int dA0 = tid * 8,        dA1 = 2048 + tid * 8;                     \
    const int dB0 = 4096 + tid * 8, dB1 = 6144 + tid * 8;                     \
    const int akey = (l16 >> 1) & 3;                                          \
    const int aoff = (wr * 64 + l16) * 32 + (quad ^ akey) * 8;                \
    const int boff = 4096 + (wc * 64 + l16) * 32 + (quad ^ akey) * 8;         \
    f4 acc[4][4] = {};

// pack two float4 (8 fp32) into one 16B bf16 vector
#define PK8(v0, v1) (u4){cvtpk(v0.x, v0.y), cvtpk(v0.z, v0.w),                \
                         cvtpk(v1.x, v1.y), cvtpk(v1.z, v1.w)}

#define GEMM_FRAGS_MFMA()                                                     \
    bf8 a[4], b[4];                                                           \
    _Pragma("unroll") for (int i = 0; i < 4; ++i) {                           \
        a[i] = *(const bf8*)(cur + aoff + i * 512);                           \
        b[i] = *(const bf8*)(cur + boff + i * 512);                           \
    }

#define GEMM_MFMA16()                                                         \
    __builtin_amdgcn_s_setprio(1);                                            \
    _Pragma("unroll") for (int mt = 0; mt < 4; ++mt)                          \
        _Pragma("unroll") for (int nt = 0; nt < 4; ++nt)                      \
            acc[mt][nt] = MFMA(a[mt], b[nt], acc[mt][nt]);                    \
    __builtin_amdgcn_s_setprio(0);

// ------------------------------------------------- qkv GEMM (fp32 in, scatter)
// C = bf16(x) @ bf16(W_qkv)^T scattered into dense Q/K/V [b][h][l][64];
// Q scaled QSC. A and B both converted fp32->bf16 during staging.
__global__ __launch_bounds__(256, 3) void gemm_qkv(const float* __restrict__ X,
                                                   const float* __restrict__ Wq,
                                                   short* __restrict__ Qd,
                                                   short* __restrict__ Kd,
                                                   short* __restrict__ Vd) {
    GEO_PROLOG();
    const float* Ax0 = X  + (size_t)(m0 + srow) * 1024 + sx;
    const float* Ax1 = Ax0 + (size_t)64 * 1024;
    const float* Bw0 = Wq + (size_t)(n0 + srow) * 1024 + sx;
    const float* Bw1 = Bw0 + (size_t)64 * 1024;
    float4 la0, la1, la2, la3, lb0, lb1, lb2, lb3;

#define QLD(ko)                                                               \
    la0 = *(const float4*)(Ax0 + (ko)); la1 = *(const float4*)(Ax0 + (ko) + 4);\
    la2 = *(const float4*)(Ax1 + (ko)); la3 = *(const float4*)(Ax1 + (ko) + 4);\
    lb0 = *(const float4*)(Bw0 + (ko)); lb1 = *(const float4*)(Bw0 + (ko) + 4);\
    lb2 = *(const float4*)(Bw1 + (ko)); lb3 = *(const float4*)(Bw1 + (ko) + 4);
#define QWR(bp)                                                               \
    *(u4*)((bp) + dA0) = PK8(la0, la1);                                       \
    *(u4*)((bp) + dA1) = PK8(la2, la3);                                       \
    *(u4*)((bp) + dB0) = PK8(lb0, lb1);                                       \
    *(u4*)((bp) + dB1) = PK8(lb2, lb3);

    short* cur = lds; short* oth = lds + BUF2;
    QLD(0); QWR(cur); QLD(32);
    BAR_LGKM();
    for (int t = 0; t < NT2; ++t) {
        GEMM_FRAGS_MFMA();
        if (t + 1 < NT2) { QWR(oth); }
        if (t + 2 < NT2) { QLD((t + 2) * 32); }
        GEMM_MFMA16();
        BAR_LGKM();
        short* tmp = cur; cur = oth; oth = tmp;
    }
#undef QLD
#undef QWR

    short* const bases[3] = {Qd, Kd, Vd};
    #pragma unroll
    for (int mt = 0; mt < 4; ++mt) {
        const int row = m0 + wr * 64 + mt * 16 + quad * 4;   // token, + r
        #pragma unroll
        for (int nt = 0; nt < 4; ++nt) {
            const int colb  = n0 + wc * 64 + nt * 16;        // + l16
            const int which = colb >> 10;                    // 0=Q 1=K 2=V
            const int hh    = (colb >> 6) & 15;
            const int d0    = colb & 63;
            const float sc_ = (which == 0) ? QSC : 1.0f;
            short* bp = bases[which];
            #pragma unroll
            for (int r = 0; r < 4; ++r) {
                const int t  = row + r;
                const int bb = t >> 11, ll = t & 2047;
                bp[((size_t)(bb * NHEAD + hh) * SEQ + ll) * 64 + d0 + l16] =
                    f2b(acc[mt][nt][r] * sc_);
            }
        }
    }
}

// ------------------------------------------------- out-proj GEMM (fp32 out)
// A = attnb (bf16, pass-through staging); B = W_out fp32 converted in staging.
__global__ __launch_bounds__(256, 3) void gemm_bt(const short* __restrict__ Ab,
                                                  const float* __restrict__ Wo,
                                                  float* __restrict__ Cp) {
    GEO_PROLOG();
    const short* Aa0 = Ab + (size_t)(m0 + srow) * 1024 + sx;
    const short* Aa1 = Aa0 + (size_t)64 * 1024;
    const float* Bw0 = Wo + (size_t)(n0 + srow) * 1024 + sx;
    const float* Bw1 = Bw0 + (size_t)64 * 1024;
    u4 ra0, ra1;
    float4 lb0, lb1, lb2, lb3;

#define TLD(ko)                                                               \
    ra0 = *(const u4*)(Aa0 + (ko));                                           \
    ra1 = *(const u4*)(Aa1 + (ko));                                           \
    lb0 = *(const float4*)(Bw0 + (ko)); lb1 = *(const float4*)(Bw0 + (ko) + 4);\
    lb2 = *(const float4*)(Bw1 + (ko)); lb3 = *(const float4*)(Bw1 + (ko) + 4);
#define TWR(bp)                                                               \
    *(u4*)((bp) + dA0) = ra0;                                                 \
    *(u4*)((bp) + dA1) = ra1;                                                 \
    *(u4*)((bp) + dB0) = PK8(lb0, lb1);                                       \
    *(u4*)((bp) + dB1) = PK8(lb2, lb3);

    short* cur = lds; short* oth = lds + BUF2;
    TLD(0); TWR(cur); TLD(32);
    BAR_LGKM();
    for (int t = 0; t < NT2; ++t) {
        GEMM_FRAGS_MFMA();
        if (t + 1 < NT2) { TWR(oth); }
        if (t + 2 < NT2) { TLD((t + 2) * 32); }
        GEMM_MFMA16();
        BAR_LGKM();
        short* tmp = cur; cur = oth; oth = tmp;
    }
#undef TLD
#undef TWR

    #pragma unroll
    for (int mt = 0; mt < 4; ++mt) {
        const int row = m0 + wr * 64 + mt * 16 + quad * 4;
        #pragma unroll
        for (int nt = 0; nt < 4; ++nt) {
            const int col = n0 + wc * 64 + nt * 16 + l16;
            #pragma unroll
            for (int r = 0; r < 4; ++r)
                Cp[(size_t)(row + r) * DIM_ + col] = acc[mt][nt][r];
        }
    }
}

// -------------------------------------------------------------- flash attention v2
// EXACT r1 version (best measured: ~63 µs) — FROZEN. Dense Q/K/V [bh][l][64]
// bf16 (Q pre-scaled). out: [B*L,1024] bf16 token-major.
// Block = 4 waves, 128 q-rows (wave w owns 32 rows, 32x32 MFMA).
// S^T = K·Q^T; P enters PV via cvt_pk_bf16 + permlane32_swap (T12).
// No-max softmax, VALU row-sum (r4's MFMA-lacc cost +10 µs; r5's dbuf+pairing
// cost +2.6 µs — do not reintroduce). Register prefetch, lgkm-only barriers,
// causal skips, setprio (T5).
__global__ __launch_bounds__(256) void flash_attn(const short* __restrict__ Qd,
                                                  const short* __restrict__ Kd,
                                                  const short* __restrict__ Vd,
                                                  short* __restrict__ out) {
    const int bh = blockIdx.x;
    const int b  = bh >> 4, h = bh & 15;
    const int qt = (gridDim.y - 1) - blockIdx.y;     // longest first
    const int q0 = qt * 128;
    const int tid  = threadIdx.x;
    const int lane = tid & 63, wave = tid >> 6;
    const int l32  = lane & 31, khalf = lane >> 5;

    __shared__ __align__(16) short Ks[64 * 72];      // K tile [key][d], LD=72
    __shared__ __align__(16) short Vt[64 * 72];      // V^T tile [d][key], LD=72
    uint32_t* Vt32 = (uint32_t*)Vt;

    const short* Qp = Qd + (size_t)bh * (SEQ * 64);
    const short* Kp = Kd + (size_t)bh * (SEQ * 64);
    const short* Vp = Vd + (size_t)bh * (SEQ * 64);

    // Q rows as persistent B-operand frags: B[k=d][n=qrow], qrow = lane&31.
    const int qrow = q0 + wave * 32 + l32;
    bf8 qf[4];
    #pragma unroll
    for (int dk = 0; dk < 4; ++dk)
        qf[dk] = *(const bf8*)(Qp + (size_t)qrow * 64 + dk * 16 + khalf * 8);

    // staging assignments
    const int skey = tid >> 2, sc = tid & 3;         // K: key row, 16B chunk
    const int vkp = tid & 31, vds = (tid >> 5) * 8;  // V: key pair, 8 dims

    // preload tile 0
    bf8 ka0 = *(const bf8*)(Kp + (size_t)skey * 64 + sc * 8);
    bf8 ka1 = *(const bf8*)(Kp + (size_t)skey * 64 + (sc + 4) * 8);
    bf8 vr0 = *(const bf8*)(Vp + (size_t)(2 * vkp) * 64 + vds);
    bf8 vr1 = *(const bf8*)(Vp + (size_t)(2 * vkp + 1) * 64 + vds);

    f16v o0 = {}, o1 = {};
    float lsum = 0.f;
    const bf8 zz = {};

    const int nIter = 2 * qt + 2;
    for (int it = 0; it < nIter; ++it) {
        const int k0 = it * 64;

        BAR_LGKM();   // prior iteration's LDS reads complete (WAR)
        *(bf8*)(&Ks[skey * 72 + sc * 8])       = ka0;
        *(bf8*)(&Ks[skey * 72 + (sc + 4) * 8]) = ka1;
        #pragma unroll
        for (int i = 0; i < 8; ++i) {
            uint32_t p = (uint32_t)(uint16_t)vr0[i] | ((uint32_t)(uint16_t)vr1[i] << 16);
            Vt32[(vds + i) * 36 + vkp] = p;
        }
        BAR_LGKM();   // writes visible; global prefetch stays outstanding

        // prefetch tile it+1
        if (it + 1 < nIter) {
            const int kn = k0 + 64;
            ka0 = *(const bf8*)(Kp + (size_t)(kn + skey) * 64 + sc * 8);
            ka1 = *(const bf8*)(Kp + (size_t)(kn + skey) * 64 + (sc + 4) * 8);
            vr0 = *(const bf8*)(Vp + (size_t)(kn + 2 * vkp) * 64 + vds);
            vr1 = *(const bf8*)(Vp + (size_t)(kn + 2 * vkp + 1) * 64 + vds);
        }

        // fully-masked iteration for this wave: no QK, no PV
        if (q0 + wave * 32 < k0) continue;

        bf8 pf[4];
        #pragma unroll
        for (int kt = 0; kt < 2; ++kt) {
            const int ktbase = k0 + kt * 32;
            const int rel = (q0 + wave * 32) - ktbase;   // wave-uniform
            if (rel < 0) {            // subtile fully above diagonal
                pf[kt * 2] = zz; pf[kt * 2 + 1] = zz;
                continue;
            }
            // S^T tile: A = K rows (m=key), B = Q rows (n=qrow)
            f16v st = {};
            __builtin_amdgcn_s_setprio(1);
            #pragma unroll
            for (int dk = 0; dk < 4; ++dk) {
                bf8 kf = *(const bf8*)(&Ks[(kt * 32 + l32) * 72 + dk * 16 + khalf * 8]);
                st = MFMA32(kf, qf[dk], st);
            }
            __builtin_amdgcn_s_setprio(0);
            // p = exp2(s); mask only on the diagonal subtile (rel == 0)
            float P[16];
            if (rel == 0) {
                #pragma unroll
                for (int r = 0; r < 16; ++r) {
                    const int kg = ktbase + (r & 3) + 8 * (r >> 2) + 4 * khalf;
                    float pv = __builtin_amdgcn_exp2f(st[r]);
                    P[r] = (kg > qrow) ? 0.0f : pv;
                }
            } else {
                #pragma unroll
                for (int r = 0; r < 16; ++r) P[r] = __builtin_amdgcn_exp2f(st[r]);
            }
            // T12: pack own P pairs to bf16 words, then permlane32_swap pairs
            // the lane<32 / lane>=32 halves — one swap fills two frag words.
            uint32_t w0 = cvtpk(P[0],  P[1]),  w1 = cvtpk(P[2],  P[3]);
            uint32_t w2 = cvtpk(P[4],  P[5]),  w3 = cvtpk(P[6],  P[7]);
            uint32_t w4 = cvtpk(P[8],  P[9]),  w5 = cvtpk(P[10], P[11]);
            uint32_t w6 = cvtpk(P[12], P[13]), w7 = cvtpk(P[14], P[15]);
            u2 s02 = __builtin_amdgcn_permlane32_swap(w0, w2, false, false);
            u2 s13 = __builtin_amdgcn_permlane32_swap(w1, w3, false, false);
            u2 s46 = __builtin_amdgcn_permlane32_swap(w4, w6, false, false);
            u2 s57 = __builtin_amdgcn_permlane32_swap(w5, w7, false, false);
            u4 q0w = {s02[0], s13[0], s02[1], s13[1]};
            u4 q1w = {s46[0], s57[0], s46[1], s57[1]};
            pf[kt * 2]     = __builtin_bit_cast(bf8, q0w);
            pf[kt * 2 + 1] = __builtin_bit_cast(bf8, q1w);
            // row-sum: own 16 P values; partner half combined in epilogue.
            float ls = ((P[0] + P[1]) + (P[2] + P[3])) +
                       ((P[4] + P[5]) + (P[6] + P[7])) +
                       ((P[8] + P[9]) + (P[10] + P[11])) +
                       ((P[12] + P[13]) + (P[14] + P[15]));
            lsum += ls;
        }

        // O += P @ V : A = pf (m=qrow), B = V^T rows (n=d)
        __builtin_amdgcn_s_setprio(1);
        #pragma unroll
        for (int ks = 0; ks < 4; ++ks) {
            bf8 v0 = *(const bf8*)(&Vt[(l32) * 72 + ks * 16 + khalf * 8]);
            bf8 v1 = *(const bf8*)(&Vt[(32 + l32) * 72 + ks * 16 + khalf * 8]);
            o0 = MFMA32(pf[ks], v0, o0);
            o1 = MFMA32(pf[ks], v1, o1);
        }
        __builtin_amdgcn_s_setprio(0);
    }

    // ---- epilogue: combine pair sums, normalize, store ----
    lsum += __shfl_xor(lsum, 32);        // lane i now holds l for qrow (i&31)
    short* outp = out + ((size_t)(b * SEQ + q0 + wave * 32) * DIM_) + h * 64;
    #pragma unroll
    for (int r = 0; r < 16; ++r) {
        const int rowl = (r & 3) + 8 * (r >> 2) + 4 * khalf;
        const float inv = 1.0f / __shfl(lsum, rowl);
        outp[(size_t)rowl * DIM_ + l32]      = f2b(o0[r] * inv);
        outp[(size_t)rowl * DIM_ + 32 + l32] = f2b(o1[r] * inv);
    }
}

// ----------------------------------------------------------------------------
extern "C" void kernel_launch(void* const* d_in, const int* in_sizes, int n_in,
                              void* d_out, int out_size, void* d_ws, size_t ws_size,
                              hipStream_t stream) {
    const float* x    = (const float*)d_in[0];   // [4,2048,1024]
    const float* wqkv = (const float*)d_in[1];   // [3072,1024]
    const float* wout = (const float*)d_in[2];   // [1024,1024]

    char* ws = (char*)d_ws;
    short* Qd    = (short*)(ws);                                   // 16 MB
    short* Kd    = (short*)(ws + (size_t)(16) * (1 << 20));        // 16 MB
    short* Vd    = (short*)(ws + (size_t)(32) * (1 << 20));        // 16 MB
    short* attnb = (short*)(ws + (size_t)(48) * (1 << 20));        // 16 MB

    // qkv = bf16(x) @ bf16(W_qkv)^T scattered into dense Q/K/V [b][h][l][64]
    // (fp32 operands converted during LDS staging — no separate cast pass)
    gemm_qkv<<<dim3(3 * DIM_ / 128, BATCH * SEQ / 128), 256, 0, stream>>>(
        x, wqkv, Qd, Kd, Vd);

    // flash attention -> attnb [8192, 1024]
    flash_attn<<<dim3(BATCH * NHEAD, SEQ / 128), 256, 0, stream>>>(Qd, Kd, Vd, attnb);

    // out = attnb @ bf16(W_out)^T : [8192, 1024] fp32
    gemm_bt<<<dim3(DIM_ / 128, BATCH * SEQ / 128), 256, 0, stream>>>(
        attnb, wout, (float*)d_out);
}

// Round 11
// 225.450 us; speedup vs baseline: 1.1382x; 1.1382x over previous
//
#include <hip/hip_runtime.h>
#include <stdint.h>

// Problem constants
#define BATCH 4
#define SEQ   2048
#define DIM_  1024
#define NHEAD 16
#define HDIM  64

// 0.125 (1/sqrt(64)) * log2(e): folded into Q so softmax is exp2(S) directly.
#define QSC 0.18033688011112042f

typedef __attribute__((ext_vector_type(8)))  short bf8;    // 8 bf16 raw bits
typedef __attribute__((ext_vector_type(4)))  short s4v;
typedef __attribute__((ext_vector_type(4)))  float f4;
typedef __attribute__((ext_vector_type(16))) float f16v;
typedef __attribute__((ext_vector_type(2)))  unsigned int u2;
typedef __attribute__((ext_vector_type(4)))  unsigned int u4;

#define MFMA(a, b, c)   __builtin_amdgcn_mfma_f32_16x16x32_bf16(a, b, c, 0, 0, 0)
#define MFMA32(a, b, c) __builtin_amdgcn_mfma_f32_32x32x16_bf16(a, b, c, 0, 0, 0)

// lgkm-only workgroup barrier: global prefetch stream stays in flight.
#define BAR_LGKM() asm volatile("s_waitcnt lgkmcnt(0)\n\ts_barrier" ::: "memory")

static __device__ __forceinline__ short f2b(float f) {
    uint32_t u = __builtin_bit_cast(uint32_t, f);
    u = (u + 0x7FFFu + ((u >> 16) & 1u)) >> 16;   // RNE
    return (short)u;
}

// packed f32x2 -> bf16x2 in one VALU op (T12; RNE, same as f2b)
static __device__ __forceinline__ uint32_t cvtpk(float lo, float hi) {
    uint32_t r;
    asm("v_cvt_pk_bf16_f32 %0, %1, %2" : "=v"(r) : "v"(lo), "v"(hi));
    return r;
}

// async global->LDS, 16 bytes/lane, offset=0 ONLY.
typedef const uint32_t __attribute__((address_space(1)))* gas_t;
typedef uint32_t __attribute__((address_space(3)))* las_t;
static __device__ __forceinline__ void gl_lds16(const short* g, short* l) {
    __builtin_amdgcn_global_load_lds((gas_t)g, (las_t)l, 16, 0, 0);
}

// ---------------------------------------------------------------- fused cast
__global__ void cvt_all(const float* __restrict__ x, const float* __restrict__ wq,
                        const float* __restrict__ wo, short* __restrict__ xb,
                        short* __restrict__ wqb, short* __restrict__ wob) {
    const int NX = BATCH * SEQ * DIM_ / 4, NQ = 3 * DIM_ * DIM_ / 4;
    int i = blockIdx.x * blockDim.x + threadIdx.x;
    const float4* in; s4v* out; int j;
    if (i < NX)           { in = (const float4*)x;  out = (s4v*)xb;  j = i; }
    else if (i < NX + NQ) { in = (const float4*)wq; out = (s4v*)wqb; j = i - NX; }
    else                  { in = (const float4*)wo; out = (s4v*)wob; j = i - NX - NQ; }
    float4 v = in[j];
    s4v o;
    o.x = f2b(v.x); o.y = f2b(v.y); o.z = f2b(v.z); o.w = f2b(v.w);
    out[j] = o;
}

// --------------------------------------------------------- wide-wave GEMM core
// r11: r8's PROVEN pipeline skeleton (triple-buffer, counted vmcnt(6), one
// barrier per K-step, same swizzle algebra) with per-wave tile 128x64 instead
// of 64x64: LDS bytes/MFMA 512 -> 384, raising the LDS-bandwidth-imposed
// MfmaUtil ceiling ~50% -> ~66% (m134: ds_read_b128 ~85 B/cyc).
// Block tile 256x128, BK=32, 4 waves (2M x 2N). LDS: A[256][32] (16 KB) +
// B[128][32] (8 KB) = 24 KB/buffer x3 = 72 KB -> 2 blocks/CU (8 waves/CU,
// independent blocks — NOT phase-locked like r3/r7's 8-wave variants).
// Swizzle (r0/r8-verified algebra): chunk c of row r holds global chunk
// c ^ ((r>>1)&3); readers use chunk quad^((l16>>1)&3); key is invariant
// across the frag index because wr*128 and i*16 contribute 0 mod (3<<1).
// Staging: 6 gl_lds/thread (A 4, B 2), linear dest (gl_lds requirement),
// pre-swizzled global source. Counted wait vmcnt(6): t+1's 6 loads done,
// t+2's 6 stay in flight. WAR-safe per r8's argument (frag ds_reads retire
// at the compiler's lgkm wait before the MFMAs, i.e. before the barrier).
#define NT3  32      /* K tiles: 1024/32 */
#define BUF3 12288   /* shorts per buffer: A 8192 + B 4096 = 24 KB */

#define PG_STAGE(bp, tt)                                                      \
    do {                                                                      \
        const int ko = (tt) * 32;                                             \
        gl_lds16(gA0 + ko, (bp) + dA0); gl_lds16(gA1 + ko, (bp) + dA1);       \
        gl_lds16(gA2 + ko, (bp) + dA2); gl_lds16(gA3 + ko, (bp) + dA3);       \
        gl_lds16(gB0 + ko, (bp) + dB0); gl_lds16(gB1 + ko, (bp) + dB1);       \
    } while (0)

// expects: A, W operand base pointers; declares geometry + acc[8][4].
#define PG_PROLOG()                                                           \
    __shared__ __align__(16) short lds[3 * BUF3];                             \
    const int tid  = threadIdx.x;                                             \
    const int lane = tid & 63;                                                \
    const int wave = tid >> 6;                                                \
    const int quad = lane >> 4, l16 = lane & 15;                              \
    const int wr = wave >> 1, wc = wave & 1;                                  \
    const int m0 = blockIdx.y * 256;                                          \
    const int n0 = blockIdx.x * 128;                                          \
    /* A staging: chunks c = j*256+tid, j=0..3; row=c>>2, pos=c&3 */          \
    const short* gA0; const short* gA1; const short* gA2; const short* gA3;   \
    const short* gB0; const short* gB1;                                       \
    int dA0, dA1, dA2, dA3, dB0, dB1;                                         \
    {                                                                         \
        const short* gat[4]; int dat[4];                                      \
        _Pragma("unroll") for (int j = 0; j < 4; ++j) {                       \
            const int c = j * 256 + tid;                                      \
            const int row = c >> 2, pos = c & 3;                              \
            gat[j] = A + (size_t)(m0 + row) * 1024 + (pos ^ ((row >> 1) & 3)) * 8; \
            dat[j] = c * 8;                                                   \
        }                                                                     \
        gA0 = gat[0]; gA1 = gat[1]; gA2 = gat[2]; gA3 = gat[3];               \
        dA0 = dat[0]; dA1 = dat[1]; dA2 = dat[2]; dA3 = dat[3];               \
        const short* gbt[2]; int dbt[2];                                      \
        _Pragma("unroll") for (int j = 0; j < 2; ++j) {                       \
            const int c = j * 256 + tid;                                      \
            const int row = c >> 2, pos = c & 3;                              \
            gbt[j] = W + (size_t)(n0 + row) * 1024 + (pos ^ ((row >> 1) & 3)) * 8; \
            dbt[j] = 8192 + c * 8;                                            \
        }                                                                     \
        gB0 = gbt[0]; gB1 = gbt[1];                                           \
        dB0 = dbt[0]; dB1 = dbt[1];                                           \
    }                                                                         \
    const int akey = (l16 >> 1) & 3;                                          \
    int aoffs[8], boffs[4];                                                   \
    _Pragma("unroll") for (int i = 0; i < 8; ++i)                             \
        aoffs[i] = (wr * 128 + i * 16 + l16) * 32 + (quad ^ akey) * 8;        \
    _Pragma("unroll") for (int i = 0; i < 4; ++i)                             \
        boffs[i] = 8192 + (wc * 64 + i * 16 + l16) * 32 + (quad ^ akey) * 8;  \
    f4 acc[8][4] = {};

#define PG_KLOOP()                                                            \
    {                                                                         \
        short* cur = lds; short* nxt = lds + BUF3; short* stg = lds + 2*BUF3; \
        PG_STAGE(cur, 0);                                                     \
        PG_STAGE(nxt, 1);                                                     \
        asm volatile("s_waitcnt vmcnt(6)\n\ts_barrier" ::: "memory");         \
        for (int t = 0; t < NT3; ++t) {                                       \
            bf8 a[8], b[4];                                                   \
            _Pragma("unroll") for (int i = 0; i < 8; ++i)                     \
                a[i] = *(const bf8*)(cur + aoffs[i]);                         \
            _Pragma("unroll") for (int i = 0; i < 4; ++i)                     \
                b[i] = *(const bf8*)(cur + boffs[i]);                         \
            if (t < NT3 - 2) PG_STAGE(stg, t + 2);                            \
            __builtin_amdgcn_s_setprio(1);                                    \
            _Pragma("unroll") for (int mt = 0; mt < 8; ++mt)                  \
                _Pragma("unroll") for (int nt = 0; nt < 4; ++nt)              \
                    acc[mt][nt] = MFMA(a[mt], b[nt], acc[mt][nt]);            \
            __builtin_amdgcn_s_setprio(0);                                    \
            if (t < NT3 - 2)                                                  \
                asm volatile("s_waitcnt vmcnt(6)\n\ts_barrier" ::: "memory"); \
            else                                                              \
                asm volatile("s_waitcnt vmcnt(0)\n\ts_barrier" ::: "memory"); \
            short* tmp = cur; cur = nxt; nxt = stg; stg = tmp;                \
        }                                                                     \
    }

// ------------------------------------------------- qkv GEMM (scatter epilogue)
// C = A @ W^T scattered into dense per-head Q/K/V [b][h][l][64]; Q scaled QSC.
__global__ __launch_bounds__(256, 2) void gemm_qkv(const short* __restrict__ A,
                                                   const short* __restrict__ W,
                                                   short* __restrict__ Qd,
                                                   short* __restrict__ Kd,
                                                   short* __restrict__ Vd) {
    PG_PROLOG();
    PG_KLOOP();

    short* const bases[3] = {Qd, Kd, Vd};
    #pragma unroll
    for (int mf = 0; mf < 8; ++mf) {
        const int row = m0 + wr * 128 + mf * 16 + quad * 4;   // token, + r
        #pragma unroll
        for (int nf = 0; nf < 4; ++nf) {
            const int colb  = n0 + wc * 64 + nf * 16;        // + l16
            const int which = colb >> 10;                    // 0=Q 1=K 2=V
            const int hh    = (colb >> 6) & 15;
            const int d0    = colb & 63;
            const float sc_ = (which == 0) ? QSC : 1.0f;
            short* bp = bases[which];
            #pragma unroll
            for (int r = 0; r < 4; ++r) {
                const int tk = row + r;
                const int bb = tk >> 11, ll = tk & 2047;
                bp[((size_t)(bb * NHEAD + hh) * SEQ + ll) * 64 + d0 + l16] =
                    f2b(acc[mf][nf][r] * sc_);
            }
        }
    }
}

// ------------------------------------------------- out-proj GEMM (fp32 out)
__global__ __launch_bounds__(256, 2) void gemm_bt(const short* __restrict__ A,
                                                  const short* __restrict__ W,
                                                  float* __restrict__ Cp) {
    PG_PROLOG();
    PG_KLOOP();

    #pragma unroll
    for (int mf = 0; mf < 8; ++mf) {
        const int row = m0 + wr * 128 + mf * 16 + quad * 4;
        #pragma unroll
        for (int nf = 0; nf < 4; ++nf) {
            const int col = n0 + wc * 64 + nf * 16 + l16;
            #pragma unroll
            for (int r = 0; r < 4; ++r)
                Cp[(size_t)(row + r) * DIM_ + col] = acc[mf][nf][r];
        }
    }
}

// -------------------------------------------------------------- flash attention v2
// EXACT r1 version (best measured: ~63 µs) — FROZEN. Dense Q/K/V [bh][l][64]
// bf16 (Q pre-scaled). out: [B*L,1024] bf16 token-major.
// Block = 4 waves, 128 q-rows (wave w owns 32 rows, 32x32 MFMA).
// S^T = K·Q^T; P enters PV via cvt_pk_bf16 + permlane32_swap (T12).
// No-max softmax, VALU row-sum (r4's MFMA-lacc cost +10 µs; r5's dbuf+pairing
// cost +2.6 µs — do not reintroduce). Register prefetch, lgkm-only barriers,
// causal skips, setprio (T5).
__global__ __launch_bounds__(256) void flash_attn(const short* __restrict__ Qd,
                                                  const short* __restrict__ Kd,
                                                  const short* __restrict__ Vd,
                                                  short* __restrict__ out) {
    const int bh = blockIdx.x;
    const int b  = bh >> 4, h = bh & 15;
    const int qt = (gridDim.y - 1) - blockIdx.y;     // longest first
    const int q0 = qt * 128;
    const int tid  = threadIdx.x;
    const int lane = tid & 63, wave = tid >> 6;
    const int l32  = lane & 31, khalf = lane >> 5;

    __shared__ __align__(16) short Ks[64 * 72];      // K tile [key][d], LD=72
    __shared__ __align__(16) short Vt[64 * 72];      // V^T tile [d][key], LD=72
    uint32_t* Vt32 = (uint32_t*)Vt;

    const short* Qp = Qd + (size_t)bh * (SEQ * 64);
    const short* Kp = Kd + (size_t)bh * (SEQ * 64);
    const short* Vp = Vd + (size_t)bh * (SEQ * 64);

    // Q rows as persistent B-operand frags: B[k=d][n=qrow], qrow = lane&31.
    const int qrow = q0 + wave * 32 + l32;
    bf8 qf[4];
    #pragma unroll
    for (int dk = 0; dk < 4; ++dk)
        qf[dk] = *(const bf8*)(Qp + (size_t)qrow * 64 + dk * 16 + khalf * 8);

    // staging assignments
    const int skey = tid >> 2, sc = tid & 3;         // K: key row, 16B chunk
    const int vkp = tid & 31, vds = (tid >> 5) * 8;  // V: key pair, 8 dims

    // preload tile 0
    bf8 ka0 = *(const bf8*)(Kp + (size_t)skey * 64 + sc * 8);
    bf8 ka1 = *(const bf8*)(Kp + (size_t)skey * 64 + (sc + 4) * 8);
    bf8 vr0 = *(const bf8*)(Vp + (size_t)(2 * vkp) * 64 + vds);
    bf8 vr1 = *(const bf8*)(Vp + (size_t)(2 * vkp + 1) * 64 + vds);

    f16v o0 = {}, o1 = {};
    float lsum = 0.f;
    const bf8 zz = {};

    const int nIter = 2 * qt + 2;
    for (int it = 0; it < nIter; ++it) {
        const int k0 = it * 64;

        BAR_LGKM();   // prior iteration's LDS reads complete (WAR)
        *(bf8*)(&Ks[skey * 72 + sc * 8])       = ka0;
        *(bf8*)(&Ks[skey * 72 + (sc + 4) * 8]) = ka1;
        #pragma unroll
        for (int i = 0; i < 8; ++i) {
            uint32_t p = (uint32_t)(uint16_t)vr0[i] | ((uint32_t)(uint16_t)vr1[i] << 16);
            Vt32[(vds + i) * 36 + vkp] = p;
        }
        BAR_LGKM();   // writes visible; global prefetch stays outstanding

        // prefetch tile it+1
        if (it + 1 < nIter) {
            const int kn = k0 + 64;
            ka0 = *(const bf8*)(Kp + (size_t)(kn + skey) * 64 + sc * 8);
            ka1 = *(const bf8*)(Kp + (size_t)(kn + skey) * 64 + (sc + 4) * 8);
            vr0 = *(const bf8*)(Vp + (size_t)(kn + 2 * vkp) * 64 + vds);
            vr1 = *(const bf8*)(Vp + (size_t)(kn + 2 * vkp + 1) * 64 + vds);
        }

        // fully-masked iteration for this wave: no QK, no PV
        if (q0 + wave * 32 < k0) continue;

        bf8 pf[4];
        #pragma unroll
        for (int kt = 0; kt < 2; ++kt) {
            const int ktbase = k0 + kt * 32;
            const int rel = (q0 + wave * 32) - ktbase;   // wave-uniform
            if (rel < 0) {            // subtile fully above diagonal
                pf[kt * 2] = zz; pf[kt * 2 + 1] = zz;
                continue;
            }
            // S^T tile: A = K rows (m=key), B = Q rows (n=qrow)
            f16v st = {};
            __builtin_amdgcn_s_setprio(1);
            #pragma unroll
            for (int dk = 0; dk < 4; ++dk) {
                bf8 kf = *(const bf8*)(&Ks[(kt * 32 + l32) * 72 + dk * 16 + khalf * 8]);
                st = MFMA32(kf, qf[dk], st);
            }
            __builtin_amdgcn_s_setprio(0);
            // p = exp2(s); mask only on the diagonal subtile (rel == 0)
            float P[16];
            if (rel == 0) {
                #pragma unroll
                for (int r = 0; r < 16; ++r) {
                    const int kg = ktbase + (r & 3) + 8 * (r >> 2) + 4 * khalf;
                    float pv = __builtin_amdgcn_exp2f(st[r]);
                    P[r] = (kg > qrow) ? 0.0f : pv;
                }
            } else {
                #pragma unroll
                for (int r = 0; r < 16; ++r) P[r] = __builtin_amdgcn_exp2f(st[r]);
            }
            // T12: pack own P pairs to bf16 words, then permlane32_swap pairs
            // the lane<32 / lane>=32 halves — one swap fills two frag words.
            uint32_t w0 = cvtpk(P[0],  P[1]),  w1 = cvtpk(P[2],  P[3]);
            uint32_t w2 = cvtpk(P[4],  P[5]),  w3 = cvtpk(P[6],  P[7]);
            uint32_t w4 = cvtpk(P[8],  P[9]),  w5 = cvtpk(P[10], P[11]);
            uint32_t w6 = cvtpk(P[12], P[13]), w7 = cvtpk(P[14], P[15]);
            u2 s02 = __builtin_amdgcn_permlane32_swap(w0, w2, false, false);
            u2 s13 = __builtin_amdgcn_permlane32_swap(w1, w3, false, false);
            u2 s46 = __builtin_amdgcn_permlane32_swap(w4, w6, false, false);
            u2 s57 = __builtin_amdgcn_permlane32_swap(w5, w7, false, false);
            u4 q0w = {s02[0], s13[0], s02[1], s13[1]};
            u4 q1w = {s46[0], s57[0], s46[1], s57[1]};
            pf[kt * 2]     = __builtin_bit_cast(bf8, q0w);
            pf[kt * 2 + 1] = __builtin_bit_cast(bf8, q1w);
            // row-sum: own 16 P values; partner half combined in epilogue.
            float ls = ((P[0] + P[1]) + (P[2] + P[3])) +
                       ((P[4] + P[5]) + (P[6] + P[7])) +
                       ((P[8] + P[9]) + (P[10] + P[11])) +
                       ((P[12] + P[13]) + (P[14] + P[15]));
            lsum += ls;
        }

        // O += P @ V : A = pf (m=qrow), B = V^T rows (n=d)
        __builtin_amdgcn_s_setprio(1);
        #pragma unroll
        for (int ks = 0; ks < 4; ++ks) {
            bf8 v0 = *(const bf8*)(&Vt[(l32) * 72 + ks * 16 + khalf * 8]);
            bf8 v1 = *(const bf8*)(&Vt[(32 + l32) * 72 + ks * 16 + khalf * 8]);
            o0 = MFMA32(pf[ks], v0, o0);
            o1 = MFMA32(pf[ks], v1, o1);
        }
        __builtin_amdgcn_s_setprio(0);
    }

    // ---- epilogue: combine pair sums, normalize, store ----
    lsum += __shfl_xor(lsum, 32);        // lane i now holds l for qrow (i&31)
    short* outp = out + ((size_t)(b * SEQ + q0 + wave * 32) * DIM_) + h * 64;
    #pragma unroll
    for (int r = 0; r < 16; ++r) {
        const int rowl = (r & 3) + 8 * (r >> 2) + 4 * khalf;
        const float inv = 1.0f / __shfl(lsum, rowl);
        outp[(size_t)rowl * DIM_ + l32]      = f2b(o0[r] * inv);
        outp[(size_t)rowl * DIM_ + 32 + l32] = f2b(o1[r] * inv);
    }
}

// ----------------------------------------------------------------------------
extern "C" void kernel_launch(void* const* d_in, const int* in_sizes, int n_in,
                              void* d_out, int out_size, void* d_ws, size_t ws_size,
                              hipStream_t stream) {
    const float* x    = (const float*)d_in[0];   // [4,2048,1024]
    const float* wqkv = (const float*)d_in[1];   // [3072,1024]
    const float* wout = (const float*)d_in[2];   // [1024,1024]

    char* ws = (char*)d_ws;
    short* xb    = (short*)(ws);                                   // 16 MB
    short* wqkvb = (short*)(ws + (size_t)(16) * (1 << 20));        //  6 MB
    short* woutb = (short*)(ws + (size_t)(22) * (1 << 20));        //  2 MB
    short* Qd    = (short*)(ws + (size_t)(24) * (1 << 20));        // 16 MB
    short* Kd    = (short*)(ws + (size_t)(40) * (1 << 20));        // 16 MB
    short* Vd    = (short*)(ws + (size_t)(56) * (1 << 20));        // 16 MB
    short* attnb = (short*)(ws + (size_t)(72) * (1 << 20));        // 16 MB

    const int ntot = (BATCH * SEQ * DIM_ + 3 * DIM_ * DIM_ + DIM_ * DIM_) / 4;
    cvt_all<<<(ntot + 255) / 256, 256, 0, stream>>>(x, wqkv, wout, xb, wqkvb, woutb);

    // qkv = x @ W_qkv^T scattered into dense Q/K/V [b][h][l][64]
    gemm_qkv<<<dim3(3 * DIM_ / 128, BATCH * SEQ / 256), 256, 0, stream>>>(
        xb, wqkvb, Qd, Kd, Vd);

    // flash attention -> attnb [8192, 1024]
    flash_attn<<<dim3(BATCH * NHEAD, SEQ / 128), 256, 0, stream>>>(Qd, Kd, Vd, attnb);

    // out = attnb @ W_out^T : [8192, 1024] fp32
    gemm_bt<<<dim3(DIM_ / 128, BATCH * SEQ / 256), 256, 0, stream>>>(
        attnb, woutb, (float*)d_out);
}